// Round 7
// baseline (438.772 us; speedup 1.0000x reference)
//
#include <hip/hip_runtime.h>
#include <math.h>

#define NPER 4096
#define MDOWN 1024
#define KNNK 32
#define CIN 64
#define DIN 67
#define KPAD 96

typedef _Float16 half8 __attribute__((ext_vector_type(8)));
typedef float f32x4 __attribute__((ext_vector_type(4)));

#define SENTU 0xFFFFFFFFFFFFFFFFULL

__device__ __forceinline__ float d2f(float qx, float qy, float qz,
                                     float px, float py, float pz) {
    float dx = __fsub_rn(qx, px);
    float dy = __fsub_rn(qy, py);
    float dz = __fsub_rn(qz, pz);
    return __fadd_rn(__fadd_rn(__fmul_rn(dx, dx), __fmul_rn(dy, dy)), __fmul_rn(dz, dz));
}

__device__ __forceinline__ float gelu_f(float y) {
    return 0.5f * y * (1.0f + erff(y * 0.70710678118654752440f));
}

__device__ __forceinline__ void insert4(unsigned long long v,
                                        unsigned long long& t0, unsigned long long& t1,
                                        unsigned long long& t2, unsigned long long& t3) {
    if (v < t3) {
        unsigned long long m2 = t2 > v ? t2 : v;
        t3 = t3 < m2 ? t3 : m2;
        unsigned long long m1 = t1 > v ? t1 : v;
        t2 = t2 < m1 ? t2 : m1;
        unsigned long long m0 = t0 > v ? t0 : v;
        t1 = t1 < m0 ? t1 : m0;
        t0 = t0 < v ? t0 : v;
    }
}

// ---------------- prep: W1 (67x128 f32) -> W1t fp16 [128][96] (zero-padded K),
//                  W2 (128x128 f32) -> W2t fp16 [128][128]
__global__ __launch_bounds__(256) void prep_kernel(const float* __restrict__ W1,
                                                   const float* __restrict__ W2,
                                                   _Float16* __restrict__ W1t,
                                                   _Float16* __restrict__ W2t) {
    int t = blockIdx.x * 256 + threadIdx.x;
    if (t < 128 * KPAD) {           // enumerate (k, c), k in [0,96), c in [0,128)
        int k = t >> 7, c = t & 127;
        float v = (k < DIN) ? W1[k * 128 + c] : 0.0f;
        W1t[(size_t)c * KPAD + k] = (_Float16)v;
    }
    int t2 = t - 128 * KPAD;
    if (t2 >= 0 && t2 < 128 * 128) {
        int k = t2 >> 7, c = t2 & 127;
        W2t[(size_t)c * 128 + k] = (_Float16)W2[t2];
    }
}

// ---------------- KNN: 1 wave per query, 4 queries per block
__global__ __launch_bounds__(256) void knn_kernel(const float* __restrict__ pos,
                                                  int* __restrict__ knn) {
    int lane = threadIdx.x & 63;
    int q = blockIdx.x * 4 + (threadIdx.x >> 6);
    int b = q >> 10;
    int i = q & 1023;
    const float* pb = pos + (size_t)b * NPER * 3;
    float qx = pb[i * 3], qy = pb[i * 3 + 1], qz = pb[i * 3 + 2];

    unsigned long long t0 = SENTU, t1 = SENTU, t2 = SENTU, t3 = SENTU;
    unsigned long long taken = 0ULL;

    for (int s = 0; s < 64; ++s) {
        int j = s * 64 + lane;
        float d2 = d2f(qx, qy, qz, pb[j * 3], pb[j * 3 + 1], pb[j * 3 + 2]);
        unsigned long long v = ((unsigned long long)__float_as_uint(d2) << 32) | (unsigned)j;
        insert4(v, t0, t1, t2, t3);
    }

    for (int r = 0; r < KNNK; ++r) {
        if (t0 == SENTU) {  // rare refill: rebuild top-4 from non-extracted candidates
            for (int s = 0; s < 64; ++s) {
                if (!((taken >> s) & 1ULL)) {
                    int j = s * 64 + lane;
                    float d2 = d2f(qx, qy, qz, pb[j * 3], pb[j * 3 + 1], pb[j * 3 + 2]);
                    unsigned long long v =
                        ((unsigned long long)__float_as_uint(d2) << 32) | (unsigned)j;
                    insert4(v, t0, t1, t2, t3);
                }
            }
        }
        unsigned long long w = t0;
        #pragma unroll
        for (int d = 1; d < 64; d <<= 1) {
            unsigned long long o = __shfl_xor(w, d, 64);
            w = o < w ? o : w;
        }
        if (t0 == w) {  // unique owner
            taken |= 1ULL << (((unsigned)(w & 0xFFFFFFFFu)) >> 6);
            t0 = t1; t1 = t2; t2 = t3; t3 = SENTU;
        }
        if (lane == 0) knn[q * KNNK + r] = (int)(unsigned)(w & 0xFFFFFFFFu);
    }
}

// ---------------- fused MLP: gather + GEMM1 + LN + GELU + GEMM2 + LN + GELU + maxpool
__global__ __launch_bounds__(256) void mlp_kernel(
    const float* __restrict__ x, const float* __restrict__ pos,
    const int* __restrict__ knn,
    const _Float16* __restrict__ W1t, const _Float16* __restrict__ W2t,
    const float* __restrict__ b1, const float* __restrict__ g1, const float* __restrict__ be1,
    const float* __restrict__ b2, const float* __restrict__ g2, const float* __restrict__ be2,
    float* __restrict__ out0) {
    __shared__ __align__(16) _Float16 A[128][KPAD];   // 24.0 KB
    __shared__ __align__(16) _Float16 H1[128][136];   // 34.8 KB
    __shared__ int jidx[128];
    __shared__ float qpos[4][3];

    int tid = threadIdx.x;
    int q0 = blockIdx.x * 4;          // 4 queries per block, all in the same batch
    int b = q0 >> 10;
    const float* pb = pos + (size_t)b * NPER * 3;

    if (tid < 128) jidx[tid] = knn[(q0 + (tid >> 5)) * KNNK + (tid & 31)];
    if (tid < 12) {
        int qq = tid / 3, comp = tid % 3;
        int iq = (q0 + qq) & 1023;
        qpos[qq][comp] = pb[iq * 3 + comp];
    }
    __syncthreads();

    // gather x features (fp16)
    for (int t = tid; t < 128 * 32; t += 256) {
        int r = t >> 5, cc = (t & 31) * 2;
        int j = jidx[r];
        float2 v = *(const float2*)(x + ((size_t)(b * NPER + j)) * CIN + cc);
        A[r][cc] = (_Float16)v.x;
        A[r][cc + 1] = (_Float16)v.y;
    }
    // rel_pos + zero pad cols 64..95
    for (int t = tid; t < 128 * 32; t += 256) {
        int r = t >> 5, c = 64 + (t & 31);
        float val = 0.0f;
        if (c < DIN) {
            int j = jidx[r];
            val = __fsub_rn(pb[j * 3 + (c - 64)], qpos[r >> 5][c - 64]);
        }
        A[r][c] = (_Float16)val;
    }
    __syncthreads();

    int lane = tid & 63, wid = tid >> 6;
    int c16 = lane & 15, g = lane >> 4;
    int r0 = wid * 32;

    f32x4 acc[2][8];
    #pragma unroll
    for (int m = 0; m < 2; ++m)
        #pragma unroll
        for (int n = 0; n < 8; ++n) acc[m][n] = (f32x4){0.f, 0.f, 0.f, 0.f};

    #pragma unroll
    for (int ks = 0; ks < 3; ++ks) {
        half8 a0 = *(const half8*)&A[r0 + c16][ks * 32 + 8 * g];
        half8 a1 = *(const half8*)&A[r0 + 16 + c16][ks * 32 + 8 * g];
        #pragma unroll
        for (int n = 0; n < 8; ++n) {
            half8 bf = *(const half8*)(W1t + (size_t)(n * 16 + c16) * KPAD + ks * 32 + 8 * g);
            acc[0][n] = __builtin_amdgcn_mfma_f32_16x16x32_f16(a0, bf, acc[0][n], 0, 0, 0);
            acc[1][n] = __builtin_amdgcn_mfma_f32_16x16x32_f16(a1, bf, acc[1][n], 0, 0, 0);
        }
    }

    // epilogue 1: bias + LN + GELU -> H1 (fp16)
    {
        float bv[8], gv[8], bev[8];
        #pragma unroll
        for (int n = 0; n < 8; ++n) {
            int c = n * 16 + c16;
            bv[n] = b1[c]; gv[n] = g1[c]; bev[n] = be1[c];
        }
        #pragma unroll
        for (int m = 0; m < 2; ++m) {
            #pragma unroll
            for (int t = 0; t < 4; ++t) {
                float s = 0.f;
                #pragma unroll
                for (int n = 0; n < 8; ++n) { acc[m][n][t] += bv[n]; s += acc[m][n][t]; }
                s += __shfl_xor(s, 1, 64); s += __shfl_xor(s, 2, 64);
                s += __shfl_xor(s, 4, 64); s += __shfl_xor(s, 8, 64);
                float mu = s * (1.0f / 128.0f);
                float vv = 0.f;
                #pragma unroll
                for (int n = 0; n < 8; ++n) { float d = acc[m][n][t] - mu; vv += d * d; }
                vv += __shfl_xor(vv, 1, 64); vv += __shfl_xor(vv, 2, 64);
                vv += __shfl_xor(vv, 4, 64); vv += __shfl_xor(vv, 8, 64);
                float rstd = rsqrtf(vv * (1.0f / 128.0f) + 1e-5f);
                int row = r0 + 16 * m + 4 * g + t;
                #pragma unroll
                for (int n = 0; n < 8; ++n) {
                    float z = (acc[m][n][t] - mu) * rstd;
                    float y = z * gv[n] + bev[n];
                    H1[row][16 * n + c16] = (_Float16)gelu_f(y);
                }
            }
        }
    }
    // no barrier needed: each wave reads back only its own 32 rows of H1

    f32x4 acc2[2][8];
    #pragma unroll
    for (int m = 0; m < 2; ++m)
        #pragma unroll
        for (int n = 0; n < 8; ++n) acc2[m][n] = (f32x4){0.f, 0.f, 0.f, 0.f};

    #pragma unroll
    for (int ks = 0; ks < 4; ++ks) {
        half8 a0 = *(const half8*)&H1[r0 + c16][ks * 32 + 8 * g];
        half8 a1 = *(const half8*)&H1[r0 + 16 + c16][ks * 32 + 8 * g];
        #pragma unroll
        for (int n = 0; n < 8; ++n) {
            half8 bf = *(const half8*)(W2t + (size_t)(n * 16 + c16) * 128 + ks * 32 + 8 * g);
            acc2[0][n] = __builtin_amdgcn_mfma_f32_16x16x32_f16(a0, bf, acc2[0][n], 0, 0, 0);
            acc2[1][n] = __builtin_amdgcn_mfma_f32_16x16x32_f16(a1, bf, acc2[1][n], 0, 0, 0);
        }
    }

    // epilogue 2: bias + LN + GELU + maxpool over K=32 (this wave's rows) -> out0
    {
        float bv[8], gv[8], bev[8];
        #pragma unroll
        for (int n = 0; n < 8; ++n) {
            int c = n * 16 + c16;
            bv[n] = b2[c]; gv[n] = g2[c]; bev[n] = be2[c];
        }
        float mx[8];
        #pragma unroll
        for (int n = 0; n < 8; ++n) mx[n] = -3.4e38f;
        #pragma unroll
        for (int m = 0; m < 2; ++m) {
            #pragma unroll
            for (int t = 0; t < 4; ++t) {
                float s = 0.f;
                #pragma unroll
                for (int n = 0; n < 8; ++n) { acc2[m][n][t] += bv[n]; s += acc2[m][n][t]; }
                s += __shfl_xor(s, 1, 64); s += __shfl_xor(s, 2, 64);
                s += __shfl_xor(s, 4, 64); s += __shfl_xor(s, 8, 64);
                float mu = s * (1.0f / 128.0f);
                float vv = 0.f;
                #pragma unroll
                for (int n = 0; n < 8; ++n) { float d = acc2[m][n][t] - mu; vv += d * d; }
                vv += __shfl_xor(vv, 1, 64); vv += __shfl_xor(vv, 2, 64);
                vv += __shfl_xor(vv, 4, 64); vv += __shfl_xor(vv, 8, 64);
                float rstd = rsqrtf(vv * (1.0f / 128.0f) + 1e-5f);
                #pragma unroll
                for (int n = 0; n < 8; ++n) {
                    float z = (acc2[m][n][t] - mu) * rstd;
                    float y = z * gv[n] + bev[n];
                    float h = gelu_f(y);
                    mx[n] = fmaxf(mx[n], h);
                }
            }
        }
        #pragma unroll
        for (int n = 0; n < 8; ++n) {
            mx[n] = fmaxf(mx[n], __shfl_xor(mx[n], 16, 64));
            mx[n] = fmaxf(mx[n], __shfl_xor(mx[n], 32, 64));
        }
        int q = q0 + wid;
        if (lane < 16) {
            #pragma unroll
            for (int n = 0; n < 8; ++n) out0[(size_t)q * 128 + n * 16 + c16] = mx[n];
        }
    }
}

// ---------------- upsample argmin + pos_down / batch_down outputs
__global__ __launch_bounds__(256) void up_kernel(const float* __restrict__ pos,
                                                 float* __restrict__ out1,
                                                 float* __restrict__ out2,
                                                 float* __restrict__ out3) {
    int b = blockIdx.x >> 5, jb = blockIdx.x & 31;
    __shared__ float pd[3072];
    __shared__ unsigned long long red[128];
    int tid = threadIdx.x;
    const float* pb = pos + (size_t)b * NPER * 3;
    for (int t = tid; t < 3072; t += 256) pd[t] = pb[t];
    __syncthreads();

    int j = jb * 128 + (tid & 127);
    int ih = tid >> 7;
    float qx = pb[j * 3], qy = pb[j * 3 + 1], qz = pb[j * 3 + 2];
    unsigned long long best = SENTU;
    int i0 = ih * 512;
    #pragma unroll 4
    for (int i = i0; i < i0 + 512; ++i) {
        float d2 = d2f(qx, qy, qz, pd[i * 3], pd[i * 3 + 1], pd[i * 3 + 2]);
        unsigned long long v = ((unsigned long long)__float_as_uint(d2) << 32) | (unsigned)i;
        best = v < best ? v : best;
    }
    if (ih == 1) red[tid & 127] = best;
    __syncthreads();
    if (ih == 0) {
        unsigned long long o = red[tid];
        best = o < best ? o : best;
        int ii = (int)(unsigned)(best & 0xFFFFFFFFu);
        out3[(size_t)b * NPER + j] = (float)(ii + b * MDOWN);
    }
    if (jb == 0) {
        for (int t = tid; t < 3072; t += 256) out1[b * 3072 + t] = pd[t];
        for (int t = tid; t < 1024; t += 256) out2[b * 1024 + t] = (float)b;
    }
}

extern "C" void kernel_launch(void* const* d_in, const int* in_sizes, int n_in,
                              void* d_out, int out_size, void* d_ws, size_t ws_size,
                              hipStream_t stream) {
    const float* x   = (const float*)d_in[0];
    const float* pos = (const float*)d_in[1];
    // d_in[2] = batch (int64), implicit — unused
    const float* W1  = (const float*)d_in[3];
    const float* b1  = (const float*)d_in[4];
    const float* g1  = (const float*)d_in[5];
    const float* be1 = (const float*)d_in[6];
    const float* W2  = (const float*)d_in[7];
    const float* b2  = (const float*)d_in[8];
    const float* g2  = (const float*)d_in[9];
    const float* be2 = (const float*)d_in[10];

    float* out  = (float*)d_out;
    float* out0 = out;                            // 8192*128
    float* out1 = out + 1048576;                  // 8192*3
    float* out2 = out + 1048576 + 24576;          // 8192
    float* out3 = out + 1048576 + 24576 + 8192;   // 32768

    int* knn = (int*)d_ws;                                        // 8192*32*4 = 1 MB
    _Float16* W1t = (_Float16*)((char*)d_ws + 8192 * 32 * 4);     // 128*96 fp16
    _Float16* W2t = W1t + 128 * KPAD;                             // 128*128 fp16

    prep_kernel<<<112, 256, 0, stream>>>(W1, W2, W1t, W2t);
    knn_kernel<<<2048, 256, 0, stream>>>(pos, knn);
    mlp_kernel<<<2048, 256, 0, stream>>>(x, pos, knn, W1t, W2t,
                                         b1, g1, be1, b2, g2, be2, out0);
    up_kernel<<<256, 256, 0, stream>>>(pos, out1, out2, out3);
}

// Round 8
// 357.527 us; speedup vs baseline: 1.2272x; 1.2272x over previous
//
#include <hip/hip_runtime.h>
#include <math.h>

#define NPER 4096
#define MDOWN 1024
#define KNNK 32
#define CIN 64
#define DIN 67
#define KPAD 96
#define SSTR 136   // shared row stride (elements) for union A/H1 buffer

typedef _Float16 half8 __attribute__((ext_vector_type(8)));
typedef _Float16 half4 __attribute__((ext_vector_type(4)));
typedef float f32x4 __attribute__((ext_vector_type(4)));

#define SENTU 0xFFFFFFFFFFFFFFFFULL

__device__ __forceinline__ float d2f(float qx, float qy, float qz,
                                     float px, float py, float pz) {
    float dx = __fsub_rn(qx, px);
    float dy = __fsub_rn(qy, py);
    float dz = __fsub_rn(qz, pz);
    return __fadd_rn(__fadd_rn(__fmul_rn(dx, dx), __fmul_rn(dy, dy)), __fmul_rn(dz, dz));
}

__device__ __forceinline__ float gelu_f(float y) {
    return 0.5f * y * (1.0f + erff(y * 0.70710678118654752440f));
}

__device__ __forceinline__ void insert4(unsigned long long v,
                                        unsigned long long& t0, unsigned long long& t1,
                                        unsigned long long& t2, unsigned long long& t3) {
    if (v < t3) {
        unsigned long long m2 = t2 > v ? t2 : v;
        t3 = t3 < m2 ? t3 : m2;
        unsigned long long m1 = t1 > v ? t1 : v;
        t2 = t2 < m1 ? t2 : m1;
        unsigned long long m0 = t0 > v ? t0 : v;
        t1 = t1 < m0 ? t1 : m0;
        t0 = t0 < v ? t0 : v;
    }
}

// ---------------- prep: W1 (67x128 f32) -> W1t fp16 [128][96] (zero-padded K),
//                  W2 (128x128 f32) -> W2t fp16 [128][128]
__global__ __launch_bounds__(256) void prep_kernel(const float* __restrict__ W1,
                                                   const float* __restrict__ W2,
                                                   _Float16* __restrict__ W1t,
                                                   _Float16* __restrict__ W2t) {
    int t = blockIdx.x * 256 + threadIdx.x;
    if (t < 128 * KPAD) {           // enumerate (k, c), k in [0,96), c in [0,128)
        int k = t >> 7, c = t & 127;
        float v = (k < DIN) ? W1[k * 128 + c] : 0.0f;
        W1t[(size_t)c * KPAD + k] = (_Float16)v;
    }
    int t2 = t - 128 * KPAD;
    if (t2 >= 0 && t2 < 128 * 128) {
        int k = t2 >> 7, c = t2 & 127;
        W2t[(size_t)c * 128 + k] = (_Float16)W2[t2];
    }
}

// ---------------- KNN: 1 wave per query, 4 queries per block (same batch),
//                  batch positions staged in LDS (48 KB)
__global__ __launch_bounds__(256) void knn_kernel(const float* __restrict__ pos,
                                                  int* __restrict__ knn) {
    __shared__ float P[NPER * 3];   // 48 KB
    int tid = threadIdx.x;
    int lane = tid & 63;
    int q = blockIdx.x * 4 + (tid >> 6);
    int b = q >> 10;
    int i = q & 1023;
    const float* pb = pos + (size_t)b * NPER * 3;
    for (int t = tid; t < NPER * 3; t += 256) P[t] = pb[t];
    __syncthreads();

    float qx = P[i * 3], qy = P[i * 3 + 1], qz = P[i * 3 + 2];

    unsigned long long t0 = SENTU, t1 = SENTU, t2 = SENTU, t3 = SENTU;
    unsigned long long taken = 0ULL;

    #pragma unroll 4
    for (int s = 0; s < 64; ++s) {
        int j = s * 64 + lane;
        float d2 = d2f(qx, qy, qz, P[j * 3], P[j * 3 + 1], P[j * 3 + 2]);
        unsigned long long v = ((unsigned long long)__float_as_uint(d2) << 32) | (unsigned)j;
        insert4(v, t0, t1, t2, t3);
    }

    for (int r = 0; r < KNNK; ++r) {
        if (t0 == SENTU) {  // rare refill: rebuild top-4 from non-extracted candidates
            for (int s = 0; s < 64; ++s) {
                if (!((taken >> s) & 1ULL)) {
                    int j = s * 64 + lane;
                    float d2 = d2f(qx, qy, qz, P[j * 3], P[j * 3 + 1], P[j * 3 + 2]);
                    unsigned long long v =
                        ((unsigned long long)__float_as_uint(d2) << 32) | (unsigned)j;
                    insert4(v, t0, t1, t2, t3);
                }
            }
        }
        unsigned long long w = t0;
        #pragma unroll
        for (int d = 1; d < 64; d <<= 1) {
            unsigned long long o = __shfl_xor(w, d, 64);
            w = o < w ? o : w;
        }
        if (t0 == w) {  // unique owner
            taken |= 1ULL << (((unsigned)(w & 0xFFFFFFFFu)) >> 6);
            t0 = t1; t1 = t2; t2 = t3; t3 = SENTU;
        }
        if (lane == 0) knn[q * KNNK + r] = (int)(unsigned)(w & 0xFFFFFFFFu);
    }
}

// ---------------- fused MLP: gather + GEMM1 + LN + GELU + GEMM2 + LN + GELU + maxpool
// Union LDS buffer: S holds A (cols 0..95) for GEMM1, then H1 (cols 0..127).
// Safe without extra barriers: each wave reads only its own 32 rows of A
// (into regs, consumed by MFMA before acc exists) and writes only its own
// 32 rows of H1; same row stride => same byte ranges per wave.
__global__ __launch_bounds__(256, 4) void mlp_kernel(
    const float* __restrict__ x, const float* __restrict__ pos,
    const int* __restrict__ knn,
    const _Float16* __restrict__ W1t, const _Float16* __restrict__ W2t,
    const float* __restrict__ b1, const float* __restrict__ g1, const float* __restrict__ be1,
    const float* __restrict__ b2, const float* __restrict__ g2, const float* __restrict__ be2,
    float* __restrict__ out0) {
    __shared__ __align__(16) _Float16 S[128][SSTR];   // 34816 B
    __shared__ int jidx[128];
    __shared__ float qpos[4][3];

    int tid = threadIdx.x;
    int q0 = blockIdx.x * 4;          // 4 queries per block, all in the same batch
    int b = q0 >> 10;
    const float* pb = pos + (size_t)b * NPER * 3;

    if (tid < 128) jidx[tid] = knn[(q0 + (tid >> 5)) * KNNK + (tid & 31)];
    if (tid < 12) {
        int qq = tid / 3, comp = tid % 3;
        int iq = (q0 + qq) & 1023;
        qpos[qq][comp] = pb[iq * 3 + comp];
    }
    __syncthreads();

    // gather x features (float4 -> half4), 128 rows x 16 chunks, 8 iters
    for (int t = tid; t < 128 * 16; t += 256) {
        int r = t >> 4, c4 = (t & 15) * 4;
        int j = jidx[r];
        float4 v = *(const float4*)(x + ((size_t)(b * NPER + j)) * CIN + c4);
        half4 hv = {(_Float16)v.x, (_Float16)v.y, (_Float16)v.z, (_Float16)v.w};
        *(half4*)&S[r][c4] = hv;
    }
    // rel_pos (cols 64..66) + zero pad (67..95), 128 rows x 8 half4-chunks, 4 iters
    for (int t = tid; t < 128 * 8; t += 256) {
        int r = t >> 3, k = t & 7;
        half4 hv = {(_Float16)0.f, (_Float16)0.f, (_Float16)0.f, (_Float16)0.f};
        if (k == 0) {
            int j = jidx[r];
            int qq = r >> 5;
            hv.x = (_Float16)__fsub_rn(pb[j * 3 + 0], qpos[qq][0]);
            hv.y = (_Float16)__fsub_rn(pb[j * 3 + 1], qpos[qq][1]);
            hv.z = (_Float16)__fsub_rn(pb[j * 3 + 2], qpos[qq][2]);
        }
        *(half4*)&S[r][64 + 4 * k] = hv;
    }
    __syncthreads();

    int lane = tid & 63, wid = tid >> 6;
    int c16 = lane & 15, g = lane >> 4;
    int r0 = wid * 32;

    f32x4 acc[2][8];
    #pragma unroll
    for (int m = 0; m < 2; ++m)
        #pragma unroll
        for (int n = 0; n < 8; ++n) acc[m][n] = (f32x4){0.f, 0.f, 0.f, 0.f};

    #pragma unroll
    for (int ks = 0; ks < 3; ++ks) {
        half8 a0 = *(const half8*)&S[r0 + c16][ks * 32 + 8 * g];
        half8 a1 = *(const half8*)&S[r0 + 16 + c16][ks * 32 + 8 * g];
        #pragma unroll
        for (int n = 0; n < 8; ++n) {
            half8 bf = *(const half8*)(W1t + (size_t)(n * 16 + c16) * KPAD + ks * 32 + 8 * g);
            acc[0][n] = __builtin_amdgcn_mfma_f32_16x16x32_f16(a0, bf, acc[0][n], 0, 0, 0);
            acc[1][n] = __builtin_amdgcn_mfma_f32_16x16x32_f16(a1, bf, acc[1][n], 0, 0, 0);
        }
    }

    // epilogue 1: bias + LN + GELU -> H1 (overwrites this wave's rows of S)
    {
        float bv[8], gv[8], bev[8];
        #pragma unroll
        for (int n = 0; n < 8; ++n) {
            int c = n * 16 + c16;
            bv[n] = b1[c]; gv[n] = g1[c]; bev[n] = be1[c];
        }
        #pragma unroll
        for (int m = 0; m < 2; ++m) {
            #pragma unroll
            for (int t = 0; t < 4; ++t) {
                float s = 0.f;
                #pragma unroll
                for (int n = 0; n < 8; ++n) { acc[m][n][t] += bv[n]; s += acc[m][n][t]; }
                s += __shfl_xor(s, 1, 64); s += __shfl_xor(s, 2, 64);
                s += __shfl_xor(s, 4, 64); s += __shfl_xor(s, 8, 64);
                float mu = s * (1.0f / 128.0f);
                float vv = 0.f;
                #pragma unroll
                for (int n = 0; n < 8; ++n) { float d = acc[m][n][t] - mu; vv += d * d; }
                vv += __shfl_xor(vv, 1, 64); vv += __shfl_xor(vv, 2, 64);
                vv += __shfl_xor(vv, 4, 64); vv += __shfl_xor(vv, 8, 64);
                float rstd = rsqrtf(vv * (1.0f / 128.0f) + 1e-5f);
                int row = r0 + 16 * m + 4 * g + t;
                #pragma unroll
                for (int n = 0; n < 8; ++n) {
                    float z = (acc[m][n][t] - mu) * rstd;
                    float y = z * gv[n] + bev[n];
                    S[row][16 * n + c16] = (_Float16)gelu_f(y);
                }
            }
        }
    }
    // no barrier needed: each wave reads back only its own 32 rows

    f32x4 acc2[2][8];
    #pragma unroll
    for (int m = 0; m < 2; ++m)
        #pragma unroll
        for (int n = 0; n < 8; ++n) acc2[m][n] = (f32x4){0.f, 0.f, 0.f, 0.f};

    #pragma unroll
    for (int ks = 0; ks < 4; ++ks) {
        half8 a0 = *(const half8*)&S[r0 + c16][ks * 32 + 8 * g];
        half8 a1 = *(const half8*)&S[r0 + 16 + c16][ks * 32 + 8 * g];
        #pragma unroll
        for (int n = 0; n < 8; ++n) {
            half8 bf = *(const half8*)(W2t + (size_t)(n * 16 + c16) * 128 + ks * 32 + 8 * g);
            acc2[0][n] = __builtin_amdgcn_mfma_f32_16x16x32_f16(a0, bf, acc2[0][n], 0, 0, 0);
            acc2[1][n] = __builtin_amdgcn_mfma_f32_16x16x32_f16(a1, bf, acc2[1][n], 0, 0, 0);
        }
    }

    // epilogue 2: bias + LN + GELU + maxpool over K=32 (this wave's rows) -> out0
    {
        float bv[8], gv[8], bev[8];
        #pragma unroll
        for (int n = 0; n < 8; ++n) {
            int c = n * 16 + c16;
            bv[n] = b2[c]; gv[n] = g2[c]; bev[n] = be2[c];
        }
        float mx[8];
        #pragma unroll
        for (int n = 0; n < 8; ++n) mx[n] = -3.4e38f;
        #pragma unroll
        for (int m = 0; m < 2; ++m) {
            #pragma unroll
            for (int t = 0; t < 4; ++t) {
                float s = 0.f;
                #pragma unroll
                for (int n = 0; n < 8; ++n) { acc2[m][n][t] += bv[n]; s += acc2[m][n][t]; }
                s += __shfl_xor(s, 1, 64); s += __shfl_xor(s, 2, 64);
                s += __shfl_xor(s, 4, 64); s += __shfl_xor(s, 8, 64);
                float mu = s * (1.0f / 128.0f);
                float vv = 0.f;
                #pragma unroll
                for (int n = 0; n < 8; ++n) { float d = acc2[m][n][t] - mu; vv += d * d; }
                vv += __shfl_xor(vv, 1, 64); vv += __shfl_xor(vv, 2, 64);
                vv += __shfl_xor(vv, 4, 64); vv += __shfl_xor(vv, 8, 64);
                float rstd = rsqrtf(vv * (1.0f / 128.0f) + 1e-5f);
                #pragma unroll
                for (int n = 0; n < 8; ++n) {
                    float z = (acc2[m][n][t] - mu) * rstd;
                    float y = z * gv[n] + bev[n];
                    float h = gelu_f(y);
                    mx[n] = fmaxf(mx[n], h);
                }
            }
        }
        #pragma unroll
        for (int n = 0; n < 8; ++n) {
            mx[n] = fmaxf(mx[n], __shfl_xor(mx[n], 16, 64));
            mx[n] = fmaxf(mx[n], __shfl_xor(mx[n], 32, 64));
        }
        int q = q0 + wid;
        if (lane < 16) {
            #pragma unroll
            for (int n = 0; n < 8; ++n) out0[(size_t)q * 128 + n * 16 + c16] = mx[n];
        }
    }
}

// ---------------- upsample argmin + pos_down / batch_down outputs
// 512 blocks: 64 queries/block, 4-way split scan (256 iters each)
__global__ __launch_bounds__(256) void up_kernel(const float* __restrict__ pos,
                                                 float* __restrict__ out1,
                                                 float* __restrict__ out2,
                                                 float* __restrict__ out3) {
    int b = blockIdx.x >> 6, jb = blockIdx.x & 63;
    __shared__ float pd[3072];
    __shared__ unsigned long long red[192];
    int tid = threadIdx.x;
    const float* pb = pos + (size_t)b * NPER * 3;
    for (int t = tid; t < 3072; t += 256) pd[t] = pb[t];
    __syncthreads();

    int qlane = tid & 63;
    int part = tid >> 6;
    int j = jb * 64 + qlane;
    float qx = pb[j * 3], qy = pb[j * 3 + 1], qz = pb[j * 3 + 2];
    unsigned long long best = SENTU;
    int i0 = part * 256;
    #pragma unroll 4
    for (int i = i0; i < i0 + 256; ++i) {
        float d2 = d2f(qx, qy, qz, pd[i * 3], pd[i * 3 + 1], pd[i * 3 + 2]);
        unsigned long long v = ((unsigned long long)__float_as_uint(d2) << 32) | (unsigned)i;
        best = v < best ? v : best;
    }
    if (part > 0) red[(part - 1) * 64 + qlane] = best;
    __syncthreads();
    if (part == 0) {
        unsigned long long o0 = red[qlane];
        unsigned long long o1 = red[64 + qlane];
        unsigned long long o2 = red[128 + qlane];
        best = o0 < best ? o0 : best;
        best = o1 < best ? o1 : best;
        best = o2 < best ? o2 : best;
        int ii = (int)(unsigned)(best & 0xFFFFFFFFu);
        out3[(size_t)b * NPER + j] = (float)(ii + b * MDOWN);
    }
    if (jb == 0) {
        for (int t = tid; t < 3072; t += 256) out1[b * 3072 + t] = pd[t];
        for (int t = tid; t < 1024; t += 256) out2[b * 1024 + t] = (float)b;
    }
}

extern "C" void kernel_launch(void* const* d_in, const int* in_sizes, int n_in,
                              void* d_out, int out_size, void* d_ws, size_t ws_size,
                              hipStream_t stream) {
    const float* x   = (const float*)d_in[0];
    const float* pos = (const float*)d_in[1];
    // d_in[2] = batch (int64), implicit — unused
    const float* W1  = (const float*)d_in[3];
    const float* b1  = (const float*)d_in[4];
    const float* g1  = (const float*)d_in[5];
    const float* be1 = (const float*)d_in[6];
    const float* W2  = (const float*)d_in[7];
    const float* b2  = (const float*)d_in[8];
    const float* g2  = (const float*)d_in[9];
    const float* be2 = (const float*)d_in[10];

    float* out  = (float*)d_out;
    float* out0 = out;                            // 8192*128
    float* out1 = out + 1048576;                  // 8192*3
    float* out2 = out + 1048576 + 24576;          // 8192
    float* out3 = out + 1048576 + 24576 + 8192;   // 32768

    int* knn = (int*)d_ws;                                        // 8192*32*4 = 1 MB
    _Float16* W1t = (_Float16*)((char*)d_ws + 8192 * 32 * 4);     // 128*96 fp16
    _Float16* W2t = W1t + 128 * KPAD;                             // 128*128 fp16

    prep_kernel<<<112, 256, 0, stream>>>(W1, W2, W1t, W2t);
    knn_kernel<<<2048, 256, 0, stream>>>(pos, knn);
    mlp_kernel<<<2048, 256, 0, stream>>>(x, pos, knn, W1t, W2t,
                                         b1, g1, be1, b2, g2, be2, out0);
    up_kernel<<<512, 256, 0, stream>>>(pos, out1, out2, out3);
}

// Round 10
// 333.456 us; speedup vs baseline: 1.3158x; 1.0722x over previous
//
#include <hip/hip_runtime.h>
#include <math.h>

#define NPER 4096
#define MDOWN 1024
#define KNNK 32
#define CIN 64
#define DIN 67
#define KPAD 96
#define SSTR 136   // shared row stride (elements) for union A/H1 buffer

typedef _Float16 half8 __attribute__((ext_vector_type(8)));
typedef _Float16 half4 __attribute__((ext_vector_type(4)));
typedef float f32x4 __attribute__((ext_vector_type(4)));

#define SENTU 0xFFFFFFFFFFFFFFFFULL

__device__ __forceinline__ float d2f(float qx, float qy, float qz,
                                     float px, float py, float pz) {
    float dx = __fsub_rn(qx, px);
    float dy = __fsub_rn(qy, py);
    float dz = __fsub_rn(qz, pz);
    return __fadd_rn(__fadd_rn(__fmul_rn(dx, dx), __fmul_rn(dy, dy)), __fmul_rn(dz, dz));
}

__device__ __forceinline__ float gelu_f(float y) {
    return 0.5f * y * (1.0f + erff(y * 0.70710678118654752440f));
}

__device__ __forceinline__ void insert4(unsigned long long v,
                                        unsigned long long& t0, unsigned long long& t1,
                                        unsigned long long& t2, unsigned long long& t3) {
    if (v < t3) {
        unsigned long long m2 = t2 > v ? t2 : v;
        t3 = t3 < m2 ? t3 : m2;
        unsigned long long m1 = t1 > v ? t1 : v;
        t2 = t2 < m1 ? t2 : m1;
        unsigned long long m0 = t0 > v ? t0 : v;
        t1 = t1 < m0 ? t1 : m0;
        t0 = t0 < v ? t0 : v;
    }
}

// ---------------- prep: W1 (67x128 f32) -> W1t fp16 [128][96] (zero-padded K),
//                  W2 (128x128 f32) -> W2t fp16 [128][128]
__global__ __launch_bounds__(256) void prep_kernel(const float* __restrict__ W1,
                                                   const float* __restrict__ W2,
                                                   _Float16* __restrict__ W1t,
                                                   _Float16* __restrict__ W2t) {
    int t = blockIdx.x * 256 + threadIdx.x;
    if (t < 128 * KPAD) {           // enumerate (k, c), k in [0,96), c in [0,128)
        int k = t >> 7, c = t & 127;
        float v = (k < DIN) ? W1[k * 128 + c] : 0.0f;
        W1t[(size_t)c * KPAD + k] = (_Float16)v;
    }
    int t2 = t - 128 * KPAD;
    if (t2 >= 0 && t2 < 128 * 128) {
        int k = t2 >> 7, c = t2 & 127;
        W2t[(size_t)c * 128 + k] = (_Float16)W2[t2];
    }
}

// ---------------- KNN: 1 wave per query, 4 queries per block (same batch),
//                  batch positions staged in LDS (48 KB)
__global__ __launch_bounds__(256) void knn_kernel(const float* __restrict__ pos,
                                                  int* __restrict__ knn) {
    __shared__ float P[NPER * 3];   // 48 KB
    int tid = threadIdx.x;
    int lane = tid & 63;
    int q = blockIdx.x * 4 + (tid >> 6);
    int b = q >> 10;
    int i = q & 1023;
    const float* pb = pos + (size_t)b * NPER * 3;
    for (int t = tid; t < NPER * 3; t += 256) P[t] = pb[t];
    __syncthreads();

    float qx = P[i * 3], qy = P[i * 3 + 1], qz = P[i * 3 + 2];

    unsigned long long t0 = SENTU, t1 = SENTU, t2 = SENTU, t3 = SENTU;
    unsigned long long taken = 0ULL;

    #pragma unroll 4
    for (int s = 0; s < 64; ++s) {
        int j = s * 64 + lane;
        float d2 = d2f(qx, qy, qz, P[j * 3], P[j * 3 + 1], P[j * 3 + 2]);
        unsigned long long v = ((unsigned long long)__float_as_uint(d2) << 32) | (unsigned)j;
        insert4(v, t0, t1, t2, t3);
    }

    for (int r = 0; r < KNNK; ++r) {
        if (t0 == SENTU) {  // rare refill: rebuild top-4 from non-extracted candidates
            for (int s = 0; s < 64; ++s) {
                if (!((taken >> s) & 1ULL)) {
                    int j = s * 64 + lane;
                    float d2 = d2f(qx, qy, qz, P[j * 3], P[j * 3 + 1], P[j * 3 + 2]);
                    unsigned long long v =
                        ((unsigned long long)__float_as_uint(d2) << 32) | (unsigned)j;
                    insert4(v, t0, t1, t2, t3);
                }
            }
        }
        unsigned long long w = t0;
        #pragma unroll
        for (int d = 1; d < 64; d <<= 1) {
            unsigned long long o = __shfl_xor(w, d, 64);
            w = o < w ? o : w;
        }
        if (t0 == w) {  // unique owner
            taken |= 1ULL << (((unsigned)(w & 0xFFFFFFFFu)) >> 6);
            t0 = t1; t1 = t2; t2 = t3; t3 = SENTU;
        }
        if (lane == 0) knn[q * KNNK + r] = (int)(unsigned)(w & 0xFFFFFFFFu);
    }
}

// ---------------- fused MLP: gather + GEMM1 + LN + GELU + GEMM2 + LN + GELU + maxpool
// Union LDS buffer: S holds A (cols 0..95) for GEMM1, then H1 (cols 0..127).
// Safe without extra barriers: each wave reads only its own 32 rows of A
// and writes only its own 32 rows of H1.
// launch_bounds(256,3): VGPR cap 170 — enough for acc[2][8]+epilogue state
// with NO scratch spill (the (256,4)/64-VGPR variant spilled: 224 MB/dispatch
// scratch writes, round 8 counters). 3 waves/SIMD = 12 waves/CU.
__global__ __launch_bounds__(256, 3) void mlp_kernel(
    const float* __restrict__ x, const float* __restrict__ pos,
    const int* __restrict__ knn,
    const _Float16* __restrict__ W1t, const _Float16* __restrict__ W2t,
    const float* __restrict__ b1, const float* __restrict__ g1, const float* __restrict__ be1,
    const float* __restrict__ b2, const float* __restrict__ g2, const float* __restrict__ be2,
    float* __restrict__ out0) {
    __shared__ __align__(16) _Float16 S[128][SSTR];   // 34816 B
    __shared__ int jidx[128];
    __shared__ float qpos[4][3];

    int tid = threadIdx.x;
    int q0 = blockIdx.x * 4;          // 4 queries per block, all in the same batch
    int b = q0 >> 10;
    const float* pb = pos + (size_t)b * NPER * 3;

    if (tid < 128) jidx[tid] = knn[(q0 + (tid >> 5)) * KNNK + (tid & 31)];
    if (tid < 12) {
        int qq = tid / 3, comp = tid % 3;
        int iq = (q0 + qq) & 1023;
        qpos[qq][comp] = pb[iq * 3 + comp];
    }
    __syncthreads();

    // gather x features (float4 -> half4), 128 rows x 16 chunks, 8 iters
    for (int t = tid; t < 128 * 16; t += 256) {
        int r = t >> 4, c4 = (t & 15) * 4;
        int j = jidx[r];
        float4 v = *(const float4*)(x + ((size_t)(b * NPER + j)) * CIN + c4);
        half4 hv = {(_Float16)v.x, (_Float16)v.y, (_Float16)v.z, (_Float16)v.w};
        *(half4*)&S[r][c4] = hv;
    }
    // rel_pos (cols 64..66) + zero pad (67..95), 128 rows x 8 half4-chunks, 4 iters
    for (int t = tid; t < 128 * 8; t += 256) {
        int r = t >> 3, k = t & 7;
        half4 hv = {(_Float16)0.f, (_Float16)0.f, (_Float16)0.f, (_Float16)0.f};
        if (k == 0) {
            int j = jidx[r];
            int qq = r >> 5;
            hv.x = (_Float16)__fsub_rn(pb[j * 3 + 0], qpos[qq][0]);
            hv.y = (_Float16)__fsub_rn(pb[j * 3 + 1], qpos[qq][1]);
            hv.z = (_Float16)__fsub_rn(pb[j * 3 + 2], qpos[qq][2]);
        }
        *(half4*)&S[r][64 + 4 * k] = hv;
    }
    __syncthreads();

    int lane = tid & 63, wid = tid >> 6;
    int c16 = lane & 15, g = lane >> 4;
    int r0 = wid * 32;

    f32x4 acc[2][8];
    #pragma unroll
    for (int m = 0; m < 2; ++m)
        #pragma unroll
        for (int n = 0; n < 8; ++n) acc[m][n] = (f32x4){0.f, 0.f, 0.f, 0.f};

    #pragma unroll
    for (int ks = 0; ks < 3; ++ks) {
        half8 a0 = *(const half8*)&S[r0 + c16][ks * 32 + 8 * g];
        half8 a1 = *(const half8*)&S[r0 + 16 + c16][ks * 32 + 8 * g];
        #pragma unroll
        for (int n = 0; n < 8; ++n) {
            half8 bf = *(const half8*)(W1t + (size_t)(n * 16 + c16) * KPAD + ks * 32 + 8 * g);
            acc[0][n] = __builtin_amdgcn_mfma_f32_16x16x32_f16(a0, bf, acc[0][n], 0, 0, 0);
            acc[1][n] = __builtin_amdgcn_mfma_f32_16x16x32_f16(a1, bf, acc[1][n], 0, 0, 0);
        }
    }

    // epilogue 1: bias + LN + GELU -> H1 (overwrites this wave's rows of S)
    {
        float bv[8], gv[8], bev[8];
        #pragma unroll
        for (int n = 0; n < 8; ++n) {
            int c = n * 16 + c16;
            bv[n] = b1[c]; gv[n] = g1[c]; bev[n] = be1[c];
        }
        #pragma unroll
        for (int m = 0; m < 2; ++m) {
            #pragma unroll
            for (int t = 0; t < 4; ++t) {
                float s = 0.f;
                #pragma unroll
                for (int n = 0; n < 8; ++n) { acc[m][n][t] += bv[n]; s += acc[m][n][t]; }
                s += __shfl_xor(s, 1, 64); s += __shfl_xor(s, 2, 64);
                s += __shfl_xor(s, 4, 64); s += __shfl_xor(s, 8, 64);
                float mu = s * (1.0f / 128.0f);
                float vv = 0.f;
                #pragma unroll
                for (int n = 0; n < 8; ++n) { float d = acc[m][n][t] - mu; vv += d * d; }
                vv += __shfl_xor(vv, 1, 64); vv += __shfl_xor(vv, 2, 64);
                vv += __shfl_xor(vv, 4, 64); vv += __shfl_xor(vv, 8, 64);
                float rstd = rsqrtf(vv * (1.0f / 128.0f) + 1e-5f);
                int row = r0 + 16 * m + 4 * g + t;
                #pragma unroll
                for (int n = 0; n < 8; ++n) {
                    float z = (acc[m][n][t] - mu) * rstd;
                    float y = z * gv[n] + bev[n];
                    S[row][16 * n + c16] = (_Float16)gelu_f(y);
                }
            }
        }
    }
    // no barrier needed: each wave reads back only its own 32 rows

    f32x4 acc2[2][8];
    #pragma unroll
    for (int m = 0; m < 2; ++m)
        #pragma unroll
        for (int n = 0; n < 8; ++n) acc2[m][n] = (f32x4){0.f, 0.f, 0.f, 0.f};

    #pragma unroll
    for (int ks = 0; ks < 4; ++ks) {
        half8 a0 = *(const half8*)&S[r0 + c16][ks * 32 + 8 * g];
        half8 a1 = *(const half8*)&S[r0 + 16 + c16][ks * 32 + 8 * g];
        #pragma unroll
        for (int n = 0; n < 8; ++n) {
            half8 bf = *(const half8*)(W2t + (size_t)(n * 16 + c16) * 128 + ks * 32 + 8 * g);
            acc2[0][n] = __builtin_amdgcn_mfma_f32_16x16x32_f16(a0, bf, acc2[0][n], 0, 0, 0);
            acc2[1][n] = __builtin_amdgcn_mfma_f32_16x16x32_f16(a1, bf, acc2[1][n], 0, 0, 0);
        }
    }

    // epilogue 2: bias + LN + GELU + maxpool over K=32 (this wave's rows) -> out0
    {
        float bv[8], gv[8], bev[8];
        #pragma unroll
        for (int n = 0; n < 8; ++n) {
            int c = n * 16 + c16;
            bv[n] = b2[c]; gv[n] = g2[c]; bev[n] = be2[c];
        }
        float mx[8];
        #pragma unroll
        for (int n = 0; n < 8; ++n) mx[n] = -3.4e38f;
        #pragma unroll
        for (int m = 0; m < 2; ++m) {
            #pragma unroll
            for (int t = 0; t < 4; ++t) {
                float s = 0.f;
                #pragma unroll
                for (int n = 0; n < 8; ++n) { acc2[m][n][t] += bv[n]; s += acc2[m][n][t]; }
                s += __shfl_xor(s, 1, 64); s += __shfl_xor(s, 2, 64);
                s += __shfl_xor(s, 4, 64); s += __shfl_xor(s, 8, 64);
                float mu = s * (1.0f / 128.0f);
                float vv = 0.f;
                #pragma unroll
                for (int n = 0; n < 8; ++n) { float d = acc2[m][n][t] - mu; vv += d * d; }
                vv += __shfl_xor(vv, 1, 64); vv += __shfl_xor(vv, 2, 64);
                vv += __shfl_xor(vv, 4, 64); vv += __shfl_xor(vv, 8, 64);
                float rstd = rsqrtf(vv * (1.0f / 128.0f) + 1e-5f);
                #pragma unroll
                for (int n = 0; n < 8; ++n) {
                    float z = (acc2[m][n][t] - mu) * rstd;
                    float y = z * gv[n] + bev[n];
                    float h = gelu_f(y);
                    mx[n] = fmaxf(mx[n], h);
                }
            }
        }
        #pragma unroll
        for (int n = 0; n < 8; ++n) {
            mx[n] = fmaxf(mx[n], __shfl_xor(mx[n], 16, 64));
            mx[n] = fmaxf(mx[n], __shfl_xor(mx[n], 32, 64));
        }
        int q = q0 + wid;
        if (lane < 16) {
            #pragma unroll
            for (int n = 0; n < 8; ++n) out0[(size_t)q * 128 + n * 16 + c16] = mx[n];
        }
    }
}

// ---------------- upsample argmin + pos_down / batch_down outputs
// 512 blocks: 64 queries/block, 4-way split scan (256 iters each)
__global__ __launch_bounds__(256) void up_kernel(const float* __restrict__ pos,
                                                 float* __restrict__ out1,
                                                 float* __restrict__ out2,
                                                 float* __restrict__ out3) {
    int b = blockIdx.x >> 6, jb = blockIdx.x & 63;
    __shared__ float pd[3072];
    __shared__ unsigned long long red[192];
    int tid = threadIdx.x;
    const float* pb = pos + (size_t)b * NPER * 3;
    for (int t = tid; t < 3072; t += 256) pd[t] = pb[t];
    __syncthreads();

    int qlane = tid & 63;
    int part = tid >> 6;
    int j = jb * 64 + qlane;
    float qx = pb[j * 3], qy = pb[j * 3 + 1], qz = pb[j * 3 + 2];
    unsigned long long best = SENTU;
    int i0 = part * 256;
    #pragma unroll 4
    for (int i = i0; i < i0 + 256; ++i) {
        float d2 = d2f(qx, qy, qz, pd[i * 3], pd[i * 3 + 1], pd[i * 3 + 2]);
        unsigned long long v = ((unsigned long long)__float_as_uint(d2) << 32) | (unsigned)i;
        best = v < best ? v : best;
    }
    if (part > 0) red[(part - 1) * 64 + qlane] = best;
    __syncthreads();
    if (part == 0) {
        unsigned long long o0 = red[qlane];
        unsigned long long o1 = red[64 + qlane];
        unsigned long long o2 = red[128 + qlane];
        best = o0 < best ? o0 : best;
        best = o1 < best ? o1 : best;
        best = o2 < best ? o2 : best;
        int ii = (int)(unsigned)(best & 0xFFFFFFFFu);
        out3[(size_t)b * NPER + j] = (float)(ii + b * MDOWN);
    }
    if (jb == 0) {
        for (int t = tid; t < 3072; t += 256) out1[b * 3072 + t] = pd[t];
        for (int t = tid; t < 1024; t += 256) out2[b * 1024 + t] = (float)b;
    }
}

extern "C" void kernel_launch(void* const* d_in, const int* in_sizes, int n_in,
                              void* d_out, int out_size, void* d_ws, size_t ws_size,
                              hipStream_t stream) {
    const float* x   = (const float*)d_in[0];
    const float* pos = (const float*)d_in[1];
    // d_in[2] = batch (int64), implicit — unused
    const float* W1  = (const float*)d_in[3];
    const float* b1  = (const float*)d_in[4];
    const float* g1  = (const float*)d_in[5];
    const float* be1 = (const float*)d_in[6];
    const float* W2  = (const float*)d_in[7];
    const float* b2  = (const float*)d_in[8];
    const float* g2  = (const float*)d_in[9];
    const float* be2 = (const float*)d_in[10];

    float* out  = (float*)d_out;
    float* out0 = out;                            // 8192*128
    float* out1 = out + 1048576;                  // 8192*3
    float* out2 = out + 1048576 + 24576;          // 8192
    float* out3 = out + 1048576 + 24576 + 8192;   // 32768

    int* knn = (int*)d_ws;                                        // 8192*32*4 = 1 MB
    _Float16* W1t = (_Float16*)((char*)d_ws + 8192 * 32 * 4);     // 128*96 fp16
    _Float16* W2t = W1t + 128 * KPAD;                             // 128*128 fp16

    prep_kernel<<<112, 256, 0, stream>>>(W1, W2, W1t, W2t);
    knn_kernel<<<2048, 256, 0, stream>>>(pos, knn);
    mlp_kernel<<<2048, 256, 0, stream>>>(x, pos, knn, W1t, W2t,
                                         b1, g1, be1, b2, g2, be2, out0);
    up_kernel<<<512, 256, 0, stream>>>(pos, out1, out2, out3);
}

// Round 11
// 250.022 us; speedup vs baseline: 1.7549x; 1.3337x over previous
//
#include <hip/hip_runtime.h>
#include <math.h>

#define NPER 4096
#define MDOWN 1024
#define KNNK 32
#define CIN 64
#define DIN 67
#define KPAD 96
#define SSTR 136   // shared row stride (elements) for union A/H1 buffer

typedef _Float16 half8 __attribute__((ext_vector_type(8)));
typedef _Float16 half4 __attribute__((ext_vector_type(4)));
typedef float f32x4 __attribute__((ext_vector_type(4)));

#define SENTU 0xFFFFFFFFFFFFFFFFULL

__device__ __forceinline__ float d2f(float qx, float qy, float qz,
                                     float px, float py, float pz) {
    float dx = __fsub_rn(qx, px);
    float dy = __fsub_rn(qy, py);
    float dz = __fsub_rn(qz, pz);
    return __fadd_rn(__fadd_rn(__fmul_rn(dx, dx), __fmul_rn(dy, dy)), __fmul_rn(dz, dz));
}

__device__ __forceinline__ float gelu_f(float y) {
    return 0.5f * y * (1.0f + erff(y * 0.70710678118654752440f));
}

__device__ __forceinline__ void insert4(unsigned long long v,
                                        unsigned long long& t0, unsigned long long& t1,
                                        unsigned long long& t2, unsigned long long& t3) {
    if (v < t3) {
        unsigned long long m2 = t2 > v ? t2 : v;
        t3 = t3 < m2 ? t3 : m2;
        unsigned long long m1 = t1 > v ? t1 : v;
        t2 = t2 < m1 ? t2 : m1;
        unsigned long long m0 = t0 > v ? t0 : v;
        t1 = t1 < m0 ? t1 : m0;
        t0 = t0 < v ? t0 : v;
    }
}

// ---------------- prep: W1 (67x128 f32) -> W1t fp16 [128][96] (zero-padded K),
//                  W2 (128x128 f32) -> W2t fp16 [128][128]
__global__ __launch_bounds__(256) void prep_kernel(const float* __restrict__ W1,
                                                   const float* __restrict__ W2,
                                                   _Float16* __restrict__ W1t,
                                                   _Float16* __restrict__ W2t) {
    int t = blockIdx.x * 256 + threadIdx.x;
    if (t < 128 * KPAD) {           // enumerate (k, c), k in [0,96), c in [0,128)
        int k = t >> 7, c = t & 127;
        float v = (k < DIN) ? W1[k * 128 + c] : 0.0f;
        W1t[(size_t)c * KPAD + k] = (_Float16)v;
    }
    int t2 = t - 128 * KPAD;
    if (t2 >= 0 && t2 < 128 * 128) {
        int k = t2 >> 7, c = t2 & 127;
        W2t[(size_t)c * 128 + k] = (_Float16)W2[t2];
    }
}

// ---------------- KNN: 1 wave per query, 4 queries per block (same batch),
//                  batch positions staged in LDS (48 KB)
__global__ __launch_bounds__(256) void knn_kernel(const float* __restrict__ pos,
                                                  int* __restrict__ knn) {
    __shared__ float P[NPER * 3];   // 48 KB
    int tid = threadIdx.x;
    int lane = tid & 63;
    int q = blockIdx.x * 4 + (tid >> 6);
    int b = q >> 10;
    int i = q & 1023;
    const float* pb = pos + (size_t)b * NPER * 3;
    for (int t = tid; t < NPER * 3; t += 256) P[t] = pb[t];
    __syncthreads();

    float qx = P[i * 3], qy = P[i * 3 + 1], qz = P[i * 3 + 2];

    unsigned long long t0 = SENTU, t1 = SENTU, t2 = SENTU, t3 = SENTU;
    unsigned long long taken = 0ULL;

    #pragma unroll 4
    for (int s = 0; s < 64; ++s) {
        int j = s * 64 + lane;
        float d2 = d2f(qx, qy, qz, P[j * 3], P[j * 3 + 1], P[j * 3 + 2]);
        unsigned long long v = ((unsigned long long)__float_as_uint(d2) << 32) | (unsigned)j;
        insert4(v, t0, t1, t2, t3);
    }

    for (int r = 0; r < KNNK; ++r) {
        if (t0 == SENTU) {  // rare refill: rebuild top-4 from non-extracted candidates
            for (int s = 0; s < 64; ++s) {
                if (!((taken >> s) & 1ULL)) {
                    int j = s * 64 + lane;
                    float d2 = d2f(qx, qy, qz, P[j * 3], P[j * 3 + 1], P[j * 3 + 2]);
                    unsigned long long v =
                        ((unsigned long long)__float_as_uint(d2) << 32) | (unsigned)j;
                    insert4(v, t0, t1, t2, t3);
                }
            }
        }
        unsigned long long w = t0;
        #pragma unroll
        for (int d = 1; d < 64; d <<= 1) {
            unsigned long long o = __shfl_xor(w, d, 64);
            w = o < w ? o : w;
        }
        if (t0 == w) {  // unique owner
            taken |= 1ULL << (((unsigned)(w & 0xFFFFFFFFu)) >> 6);
            t0 = t1; t1 = t2; t2 = t3; t3 = SENTU;
        }
        if (lane == 0) knn[q * KNNK + r] = (int)(unsigned)(w & 0xFFFFFFFFu);
    }
}

// ---------------- fused MLP: gather + GEMM1 + LN + GELU + GEMM2 + LN + GELU + maxpool
// 512 threads / 8 waves per block; each wave owns ONE 16-row tile (16x128 output).
// acc footprint halves vs the 32-row variant: acc[8] = 32 f32/lane — the 32-row
// version needed ~140-200 regs naturally and spilled under any cap (rounds 8/10:
// 113-224 MB/dispatch scratch writes). Cap 128 via launch_bounds(512,4) -> 16
// waves/CU, target: no spill.
// Union LDS buffer S: A (cols 0..95) for GEMM1, then H1 (cols 0..127); each wave
// touches only its own 16 rows between barriers. Maxpool combines wave pairs
// through a 4 KB pmax buffer + one barrier.
__global__ __launch_bounds__(512, 4) void mlp_kernel(
    const float* __restrict__ x, const float* __restrict__ pos,
    const int* __restrict__ knn,
    const _Float16* __restrict__ W1t, const _Float16* __restrict__ W2t,
    const float* __restrict__ b1, const float* __restrict__ g1, const float* __restrict__ be1,
    const float* __restrict__ b2, const float* __restrict__ g2, const float* __restrict__ be2,
    float* __restrict__ out0) {
    __shared__ __align__(16) _Float16 S[128][SSTR];   // 34816 B
    __shared__ float pmax[8][128];                    // 4 KB
    __shared__ int jidx[128];
    __shared__ float qpos[4][3];

    int tid = threadIdx.x;
    int q0 = blockIdx.x * 4;          // 4 queries per block, all in the same batch
    int b = q0 >> 10;
    const float* pb = pos + (size_t)b * NPER * 3;

    if (tid < 128) jidx[tid] = knn[(q0 + (tid >> 5)) * KNNK + (tid & 31)];
    if (tid < 12) {
        int qq = tid / 3, comp = tid % 3;
        int iq = (q0 + qq) & 1023;
        qpos[qq][comp] = pb[iq * 3 + comp];
    }
    __syncthreads();

    // gather x features (float4 -> half4), 128 rows x 16 chunks, 4 iters
    for (int t = tid; t < 128 * 16; t += 512) {
        int r = t >> 4, c4 = (t & 15) * 4;
        int j = jidx[r];
        float4 v = *(const float4*)(x + ((size_t)(b * NPER + j)) * CIN + c4);
        half4 hv = {(_Float16)v.x, (_Float16)v.y, (_Float16)v.z, (_Float16)v.w};
        *(half4*)&S[r][c4] = hv;
    }
    // rel_pos (cols 64..66) + zero pad (67..95), 128 rows x 8 half4-chunks, 2 iters
    for (int t = tid; t < 128 * 8; t += 512) {
        int r = t >> 3, k = t & 7;
        half4 hv = {(_Float16)0.f, (_Float16)0.f, (_Float16)0.f, (_Float16)0.f};
        if (k == 0) {
            int j = jidx[r];
            int qq = r >> 5;
            hv.x = (_Float16)__fsub_rn(pb[j * 3 + 0], qpos[qq][0]);
            hv.y = (_Float16)__fsub_rn(pb[j * 3 + 1], qpos[qq][1]);
            hv.z = (_Float16)__fsub_rn(pb[j * 3 + 2], qpos[qq][2]);
        }
        *(half4*)&S[r][64 + 4 * k] = hv;
    }
    __syncthreads();

    int lane = tid & 63, wid = tid >> 6;     // wid 0..7: 16-row tile index
    int c16 = lane & 15, g = lane >> 4;
    int r0 = wid * 16;

    f32x4 acc[8];
    #pragma unroll
    for (int n = 0; n < 8; ++n) acc[n] = (f32x4){0.f, 0.f, 0.f, 0.f};

    #pragma unroll
    for (int ks = 0; ks < 3; ++ks) {
        half8 a = *(const half8*)&S[r0 + c16][ks * 32 + 8 * g];
        #pragma unroll
        for (int n = 0; n < 8; ++n) {
            half8 bf = *(const half8*)(W1t + (size_t)(n * 16 + c16) * KPAD + ks * 32 + 8 * g);
            acc[n] = __builtin_amdgcn_mfma_f32_16x16x32_f16(a, bf, acc[n], 0, 0, 0);
        }
    }

    // epilogue 1: bias + LN + GELU -> H1 (overwrites this wave's 16 rows of S)
    {
        float bv[8], gv[8], bev[8];
        #pragma unroll
        for (int n = 0; n < 8; ++n) {
            int c = n * 16 + c16;
            bv[n] = b1[c]; gv[n] = g1[c]; bev[n] = be1[c];
        }
        #pragma unroll
        for (int t = 0; t < 4; ++t) {
            float s = 0.f;
            #pragma unroll
            for (int n = 0; n < 8; ++n) { acc[n][t] += bv[n]; s += acc[n][t]; }
            s += __shfl_xor(s, 1, 64); s += __shfl_xor(s, 2, 64);
            s += __shfl_xor(s, 4, 64); s += __shfl_xor(s, 8, 64);
            float mu = s * (1.0f / 128.0f);
            float vv = 0.f;
            #pragma unroll
            for (int n = 0; n < 8; ++n) { float d = acc[n][t] - mu; vv += d * d; }
            vv += __shfl_xor(vv, 1, 64); vv += __shfl_xor(vv, 2, 64);
            vv += __shfl_xor(vv, 4, 64); vv += __shfl_xor(vv, 8, 64);
            float rstd = rsqrtf(vv * (1.0f / 128.0f) + 1e-5f);
            int row = r0 + 4 * g + t;
            #pragma unroll
            for (int n = 0; n < 8; ++n) {
                float z = (acc[n][t] - mu) * rstd;
                float y = z * gv[n] + bev[n];
                S[row][16 * n + c16] = (_Float16)gelu_f(y);
            }
        }
    }
    // no barrier needed: each wave reads back only its own 16 rows

    f32x4 acc2[8];
    #pragma unroll
    for (int n = 0; n < 8; ++n) acc2[n] = (f32x4){0.f, 0.f, 0.f, 0.f};

    #pragma unroll
    for (int ks = 0; ks < 4; ++ks) {
        half8 a = *(const half8*)&S[r0 + c16][ks * 32 + 8 * g];
        #pragma unroll
        for (int n = 0; n < 8; ++n) {
            half8 bf = *(const half8*)(W2t + (size_t)(n * 16 + c16) * 128 + ks * 32 + 8 * g);
            acc2[n] = __builtin_amdgcn_mfma_f32_16x16x32_f16(a, bf, acc2[n], 0, 0, 0);
        }
    }

    // epilogue 2: bias + LN + GELU + partial maxpool over this wave's 16 rows
    {
        float bv[8], gv[8], bev[8];
        #pragma unroll
        for (int n = 0; n < 8; ++n) {
            int c = n * 16 + c16;
            bv[n] = b2[c]; gv[n] = g2[c]; bev[n] = be2[c];
        }
        float mx[8];
        #pragma unroll
        for (int n = 0; n < 8; ++n) mx[n] = -3.4e38f;
        #pragma unroll
        for (int t = 0; t < 4; ++t) {
            float s = 0.f;
            #pragma unroll
            for (int n = 0; n < 8; ++n) { acc2[n][t] += bv[n]; s += acc2[n][t]; }
            s += __shfl_xor(s, 1, 64); s += __shfl_xor(s, 2, 64);
            s += __shfl_xor(s, 4, 64); s += __shfl_xor(s, 8, 64);
            float mu = s * (1.0f / 128.0f);
            float vv = 0.f;
            #pragma unroll
            for (int n = 0; n < 8; ++n) { float d = acc2[n][t] - mu; vv += d * d; }
            vv += __shfl_xor(vv, 1, 64); vv += __shfl_xor(vv, 2, 64);
            vv += __shfl_xor(vv, 4, 64); vv += __shfl_xor(vv, 8, 64);
            float rstd = rsqrtf(vv * (1.0f / 128.0f) + 1e-5f);
            #pragma unroll
            for (int n = 0; n < 8; ++n) {
                float z = (acc2[n][t] - mu) * rstd;
                float y = z * gv[n] + bev[n];
                float h = gelu_f(y);
                mx[n] = fmaxf(mx[n], h);
            }
        }
        #pragma unroll
        for (int n = 0; n < 8; ++n) {
            mx[n] = fmaxf(mx[n], __shfl_xor(mx[n], 16, 64));
            mx[n] = fmaxf(mx[n], __shfl_xor(mx[n], 32, 64));
        }
        if (lane < 16) {
            #pragma unroll
            for (int n = 0; n < 8; ++n) pmax[wid][n * 16 + c16] = mx[n];
        }
    }
    __syncthreads();

    // combine wave pairs: query q (0..3) = waves 2q, 2q+1
    {
        int q = tid >> 7, c = tid & 127;
        out0[(size_t)(q0 + q) * 128 + c] = fmaxf(pmax[2 * q][c], pmax[2 * q + 1][c]);
    }
}

// ---------------- upsample argmin + pos_down / batch_down outputs
// 512 blocks: 64 queries/block, 4-way split scan (256 iters each)
__global__ __launch_bounds__(256) void up_kernel(const float* __restrict__ pos,
                                                 float* __restrict__ out1,
                                                 float* __restrict__ out2,
                                                 float* __restrict__ out3) {
    int b = blockIdx.x >> 6, jb = blockIdx.x & 63;
    __shared__ float pd[3072];
    __shared__ unsigned long long red[192];
    int tid = threadIdx.x;
    const float* pb = pos + (size_t)b * NPER * 3;
    for (int t = tid; t < 3072; t += 256) pd[t] = pb[t];
    __syncthreads();

    int qlane = tid & 63;
    int part = tid >> 6;
    int j = jb * 64 + qlane;
    float qx = pb[j * 3], qy = pb[j * 3 + 1], qz = pb[j * 3 + 2];
    unsigned long long best = SENTU;
    int i0 = part * 256;
    #pragma unroll 4
    for (int i = i0; i < i0 + 256; ++i) {
        float d2 = d2f(qx, qy, qz, pd[i * 3], pd[i * 3 + 1], pd[i * 3 + 2]);
        unsigned long long v = ((unsigned long long)__float_as_uint(d2) << 32) | (unsigned)i;
        best = v < best ? v : best;
    }
    if (part > 0) red[(part - 1) * 64 + qlane] = best;
    __syncthreads();
    if (part == 0) {
        unsigned long long o0 = red[qlane];
        unsigned long long o1 = red[64 + qlane];
        unsigned long long o2 = red[128 + qlane];
        best = o0 < best ? o0 : best;
        best = o1 < best ? o1 : best;
        best = o2 < best ? o2 : best;
        int ii = (int)(unsigned)(best & 0xFFFFFFFFu);
        out3[(size_t)b * NPER + j] = (float)(ii + b * MDOWN);
    }
    if (jb == 0) {
        for (int t = tid; t < 3072; t += 256) out1[b * 3072 + t] = pd[t];
        for (int t = tid; t < 1024; t += 256) out2[b * 1024 + t] = (float)b;
    }
}

extern "C" void kernel_launch(void* const* d_in, const int* in_sizes, int n_in,
                              void* d_out, int out_size, void* d_ws, size_t ws_size,
                              hipStream_t stream) {
    const float* x   = (const float*)d_in[0];
    const float* pos = (const float*)d_in[1];
    // d_in[2] = batch (int64), implicit — unused
    const float* W1  = (const float*)d_in[3];
    const float* b1  = (const float*)d_in[4];
    const float* g1  = (const float*)d_in[5];
    const float* be1 = (const float*)d_in[6];
    const float* W2  = (const float*)d_in[7];
    const float* b2  = (const float*)d_in[8];
    const float* g2  = (const float*)d_in[9];
    const float* be2 = (const float*)d_in[10];

    float* out  = (float*)d_out;
    float* out0 = out;                            // 8192*128
    float* out1 = out + 1048576;                  // 8192*3
    float* out2 = out + 1048576 + 24576;          // 8192
    float* out3 = out + 1048576 + 24576 + 8192;   // 32768

    int* knn = (int*)d_ws;                                        // 8192*32*4 = 1 MB
    _Float16* W1t = (_Float16*)((char*)d_ws + 8192 * 32 * 4);     // 128*96 fp16
    _Float16* W2t = W1t + 128 * KPAD;                             // 128*128 fp16

    prep_kernel<<<112, 256, 0, stream>>>(W1, W2, W1t, W2t);
    knn_kernel<<<2048, 256, 0, stream>>>(pos, knn);
    mlp_kernel<<<1024, 512, 0, stream>>>(x, pos, knn, W1t, W2t,
                                         b1, g1, be1, b2, g2, be2, out0);
    up_kernel<<<512, 256, 0, stream>>>(pos, out1, out2, out3);
}